// Round 4
// baseline (223.183 us; speedup 1.0000x reference)
//
#include <hip/hip_runtime.h>

#define NN 1024
#define MM 1024
#define DD 256

typedef float floatx2 __attribute__((ext_vector_type(2)));

__device__ __forceinline__ float rcp_fast(float x) { return __builtin_amdgcn_rcpf(x); }

// ---------------- K1: fused dual GEMM + exp epilogue ----------------
// q = f_r @ W_w^T + W_b      -> Eq[n][d]  = exp(2q)
// k = f_rp @ Wp_w^T + Wp_b   -> EkT[d][m] = exp(2k)  (transposed via LDS, coalesced stores)
// Block 0 also zeroes the last-block counter used by K4.
__global__ __launch_bounds__(256) void gemm_exp_kernel(
    const float* __restrict__ f_r,  const float* __restrict__ W_w,  const float* __restrict__ W_b,
    const float* __restrict__ f_rp, const float* __restrict__ Wp_w, const float* __restrict__ Wp_b,
    float* __restrict__ Eq, float* __restrict__ EkT, unsigned int* __restrict__ cnt)
{
    const int b    = blockIdx.x;
    const int mat  = b >> 7;
    const int tile = b & 127;
    const int rt = tile & 31, dt = tile >> 5;
    const float* __restrict__ A    = mat ? f_rp : f_r;
    const float* __restrict__ B    = mat ? Wp_w : W_w;
    const float* __restrict__ bias = mat ? Wp_b : W_b;

    __shared__ float As[32][36];   // [k][r]
    __shared__ float Bs[32][68];   // [k][d]
    __shared__ float T[64][36];    // k-path transpose buffer [d_local][r_local]

    const int t  = threadIdx.x;
    if (b == 0 && t == 0) *cnt = 0;              // reset K4's last-block counter
    const int tx = t & 15, ty = t >> 4;          // tx -> 4 d-cols, ty -> 2 r-rows
    const int r0 = rt * 32, d0 = dt * 64;
    const int ar = t >> 3, ak = (t & 7) * 4;     // A stage: 32 rows x 32 k
    const int br = t >> 2, bk = (t & 3) * 8;     // B stage: 64 rows x 32 k

    float acc[2][4];
    #pragma unroll
    for (int i = 0; i < 2; ++i)
        #pragma unroll
        for (int j = 0; j < 4; ++j) acc[i][j] = 0.f;

    for (int kk = 0; kk < DD; kk += 32) {
        float4 av  = *(const float4*)(A + (size_t)(r0 + ar) * DD + kk + ak);
        float4 bv0 = *(const float4*)(B + (size_t)(d0 + br) * DD + kk + bk);
        float4 bv1 = *(const float4*)(B + (size_t)(d0 + br) * DD + kk + bk + 4);
        __syncthreads();
        As[ak + 0][ar] = av.x; As[ak + 1][ar] = av.y; As[ak + 2][ar] = av.z; As[ak + 3][ar] = av.w;
        Bs[bk + 0][br] = bv0.x; Bs[bk + 1][br] = bv0.y; Bs[bk + 2][br] = bv0.z; Bs[bk + 3][br] = bv0.w;
        Bs[bk + 4][br] = bv1.x; Bs[bk + 5][br] = bv1.y; Bs[bk + 6][br] = bv1.z; Bs[bk + 7][br] = bv1.w;
        __syncthreads();
        #pragma unroll
        for (int k = 0; k < 32; ++k) {
            float2 a2 = *(const float2*)&As[k][ty * 2];
            float4 b4 = *(const float4*)&Bs[k][tx * 4];
            float aa[2] = {a2.x, a2.y};
            float bb[4] = {b4.x, b4.y, b4.z, b4.w};
            #pragma unroll
            for (int i = 0; i < 2; ++i)
                #pragma unroll
                for (int j = 0; j < 4; ++j)
                    acc[i][j] = fmaf(aa[i], bb[j], acc[i][j]);
        }
    }

    float bj[4];
    #pragma unroll
    for (int j = 0; j < 4; ++j) bj[j] = bias[d0 + tx * 4 + j];

    float e[2][4];
    #pragma unroll
    for (int i = 0; i < 2; ++i)
        #pragma unroll
        for (int j = 0; j < 4; ++j) {
            float v = acc[i][j] + bj[j];
            // +-10: tanh fully saturated; keeps pair-products (e^40)^2 < fp32 max
            v = fminf(fmaxf(v, -10.f), 10.f);
            e[i][j] = __expf(2.f * v);
        }

    if (mat == 0) {
        #pragma unroll
        for (int i = 0; i < 2; ++i)
            *(float4*)&Eq[(size_t)(r0 + ty * 2 + i) * DD + d0 + tx * 4] =
                make_float4(e[i][0], e[i][1], e[i][2], e[i][3]);
    } else {
        __syncthreads();
        #pragma unroll
        for (int i = 0; i < 2; ++i)
            #pragma unroll
            for (int j = 0; j < 4; ++j) T[tx * 4 + j][ty * 2 + i] = e[i][j];
        __syncthreads();
        const int dl = t >> 3, rl = (t & 7) * 4;
        #pragma unroll
        for (int h = 0; h < 2; ++h) {
            int dloc = dl + 32 * h;
            float4 tv = *(const float4*)&T[dloc][rl];
            *(float4*)&EkT[(size_t)(d0 + dloc) * MM + r0 + rl] = tv;
        }
    }
}

// ---------------- K2: scores + softmax over m -> alpha ----------------
// s~[n,m] = sum_d (-2 w[d]) * rcp(Eq[n,d]*Ek[m,d] + 1)
// Pairwise: w0/x0 + w1/x1 = (w0*x1 + w1*x0) * rcp(x0*x1)  -> half the rcp count.
// j-dimension packed as floatx2 to get v_pk_fma_f32; explicit next-g prefetch.
// 512 blocks x 512 thr; block = 2 n-rows; tg = d-half; tm -> m cols 4tm..4tm+3.
__global__ __launch_bounds__(512, 4) void score_softmax_kernel(
    const float* __restrict__ Eq, const float* __restrict__ EkT,
    const float* __restrict__ w_w, float* __restrict__ alpha)
{
    __shared__ float eq[2 * DD];
    __shared__ float w2[DD];
    __shared__ float accbuf[8][256];
    __shared__ float redmx[8 * 2];
    __shared__ float redsm[8 * 2];

    const int t  = threadIdx.x;
    const int tg = t >> 8;        // d-half
    const int tm = t & 255;       // m cols 4tm..4tm+3
    const int lane = t & 63, wid = t >> 6;
    const int n0 = blockIdx.x * 2;
    const int dh = tg * 128;

    eq[t] = Eq[(size_t)n0 * DD + t];
    if (t < DD) w2[t] = -2.0f * w_w[t];
    __syncthreads();

    const floatx2 one2 = {1.f, 1.f};
    floatx2 accl[2] = {{0.f, 0.f}, {0.f, 0.f}};   // j0,j1 per n
    floatx2 acch[2] = {{0.f, 0.f}, {0.f, 0.f}};   // j2,j3 per n

    const float* ekb = EkT + (size_t)dh * MM + 4 * tm;

    float4 c0 = *(const float4*)(ekb + 0 * MM);
    float4 c1 = *(const float4*)(ekb + 1 * MM);
    float4 c2 = *(const float4*)(ekb + 2 * MM);
    float4 c3 = *(const float4*)(ekb + 3 * MM);

    for (int g = 0; g < 32; ++g) {
        float4 p0, p1, p2, p3;
        if (g < 31) {
            const float* nb = ekb + (size_t)(g * 4 + 4) * MM;
            p0 = *(const float4*)(nb + 0 * MM);
            p1 = *(const float4*)(nb + 1 * MM);
            p2 = *(const float4*)(nb + 2 * MM);
            p3 = *(const float4*)(nb + 3 * MM);
        }
        const int db = g * 4;
        float4 w4 = *(const float4*)&w2[dh + db];
        float4 qA = *(const float4*)&eq[dh + db];
        float4 qB = *(const float4*)&eq[DD + dh + db];

        floatx2 k0l = {c0.x, c0.y}, k0h = {c0.z, c0.w};
        floatx2 k1l = {c1.x, c1.y}, k1h = {c1.z, c1.w};
        floatx2 k2l = {c2.x, c2.y}, k2h = {c2.z, c2.w};
        floatx2 k3l = {c3.x, c3.y}, k3h = {c3.z, c3.w};
        floatx2 wa0 = {w4.x, w4.x}, wb0 = {w4.y, w4.y};
        floatx2 wa1 = {w4.z, w4.z}, wb1 = {w4.w, w4.w};
        float qs[2][4] = {{qA.x, qA.y, qA.z, qA.w}, {qB.x, qB.y, qB.z, qB.w}};

        #pragma unroll
        for (int n = 0; n < 2; ++n) {
            floatx2 qa0 = {qs[n][0], qs[n][0]}, qb0 = {qs[n][1], qs[n][1]};
            floatx2 qa1 = {qs[n][2], qs[n][2]}, qb1 = {qs[n][3], qs[n][3]};
            // pair (d0,d1), lo half (j0,j1)
            floatx2 x0 = qa0 * k0l + one2, x1 = qb0 * k1l + one2;
            floatx2 pr = x0 * x1;
            floatx2 tn = wa0 * x1 + wb0 * x0;
            floatx2 r;  r.x = rcp_fast(pr.x);  r.y = rcp_fast(pr.y);
            accl[n] += tn * r;
            // pair (d0,d1), hi half (j2,j3)
            x0 = qa0 * k0h + one2; x1 = qb0 * k1h + one2;
            pr = x0 * x1; tn = wa0 * x1 + wb0 * x0;
            r.x = rcp_fast(pr.x);  r.y = rcp_fast(pr.y);
            acch[n] += tn * r;
            // pair (d2,d3), lo half
            x0 = qa1 * k2l + one2; x1 = qb1 * k3l + one2;
            pr = x0 * x1; tn = wa1 * x1 + wb1 * x0;
            r.x = rcp_fast(pr.x);  r.y = rcp_fast(pr.y);
            accl[n] += tn * r;
            // pair (d2,d3), hi half
            x0 = qa1 * k2h + one2; x1 = qb1 * k3h + one2;
            pr = x0 * x1; tn = wa1 * x1 + wb1 * x0;
            r.x = rcp_fast(pr.x);  r.y = rcp_fast(pr.y);
            acch[n] += tn * r;
        }
        c0 = p0; c1 = p1; c2 = p2; c3 = p3;
    }

    float acc[2][4];
    #pragma unroll
    for (int n = 0; n < 2; ++n) {
        acc[n][0] = accl[n].x; acc[n][1] = accl[n].y;
        acc[n][2] = acch[n].x; acc[n][3] = acch[n].y;
    }

    // combine d-halves
    if (tg == 1) {
        #pragma unroll
        for (int n = 0; n < 2; ++n)
            #pragma unroll
            for (int j = 0; j < 4; ++j) accbuf[n * 4 + j][tm] = acc[n][j];
    }
    __syncthreads();
    if (tg == 0) {
        #pragma unroll
        for (int n = 0; n < 2; ++n)
            #pragma unroll
            for (int j = 0; j < 4; ++j) acc[n][j] += accbuf[n * 4 + j][tm];
    }

    // softmax over m: max
    float mx[2];
    #pragma unroll
    for (int n = 0; n < 2; ++n) {
        mx[n] = (tg == 0) ? fmaxf(fmaxf(acc[n][0], acc[n][1]), fmaxf(acc[n][2], acc[n][3])) : -3e38f;
        #pragma unroll
        for (int off = 32; off > 0; off >>= 1) mx[n] = fmaxf(mx[n], __shfl_xor(mx[n], off));
    }
    if (lane == 0) { redmx[wid * 2] = mx[0]; redmx[wid * 2 + 1] = mx[1]; }
    __syncthreads();
    float MX[2];
    #pragma unroll
    for (int n = 0; n < 2; ++n) {
        float m = redmx[n];
        #pragma unroll
        for (int w = 1; w < 8; ++w) m = fmaxf(m, redmx[w * 2 + n]);
        MX[n] = m;
    }

    // exp + sum
    float e[2][4], sm[2];
    #pragma unroll
    for (int n = 0; n < 2; ++n) {
        sm[n] = 0.f;
        #pragma unroll
        for (int j = 0; j < 4; ++j) {
            e[n][j] = (tg == 0) ? __expf(acc[n][j] - MX[n]) : 0.f;
            sm[n] += e[n][j];
        }
        #pragma unroll
        for (int off = 32; off > 0; off >>= 1) sm[n] += __shfl_xor(sm[n], off);
    }
    if (lane == 0) { redsm[wid * 2] = sm[0]; redsm[wid * 2 + 1] = sm[1]; }
    __syncthreads();
    if (tg == 0) {
        #pragma unroll
        for (int n = 0; n < 2; ++n) {
            float s = redsm[n];
            #pragma unroll
            for (int w = 1; w < 8; ++w) s += redsm[w * 2 + n];
            float inv = rcp_fast(s);
            *(float4*)&alpha[(size_t)(n0 + n) * MM + 4 * tm] =
                make_float4(e[n][0] * inv, e[n][1] * inv, e[n][2] * inv, e[n][3] * inv);
        }
    }
}

// ---------------- K3: context GEMM, part[ms] = alpha_tile @ frp_tile ----------------
// tile: 16 n x 256 d, m-split 8 -> 64 x 8 = 512 blocks x 256 thr.
__global__ __launch_bounds__(256) void context_kernel(
    const float* __restrict__ alpha, const float* __restrict__ frp,
    float* __restrict__ part)
{
    __shared__ float als[16][128];   // alpha tile, broadcast reads (wave-uniform row)
    const int t  = threadIdx.x;
    const int bm = blockIdx.x & 7;
    const int bn = blockIdx.x >> 3;
    const int dq = t & 63;           // 4 d-cols: 4dq..4dq+3
    const int ng = t >> 6;           // n-subgroup (== wave id -> broadcast)

    #pragma unroll
    for (int i = 0; i < 2; ++i) {
        int f4i = t + i * 256;
        int row = f4i >> 5, c4 = f4i & 31;
        *(float4*)&als[row][c4 * 4] =
            *(const float4*)&alpha[(size_t)(bn * 16 + row) * MM + bm * 128 + c4 * 4];
    }
    __syncthreads();

    float acc[4][4];
    #pragma unroll
    for (int n = 0; n < 4; ++n)
        #pragma unroll
        for (int j = 0; j < 4; ++j) acc[n][j] = 0.f;

    const float* fb = frp + (size_t)(bm * 128) * DD + 4 * dq;
    for (int m4 = 0; m4 < 32; ++m4) {
        float av[4][4];
        #pragma unroll
        for (int n = 0; n < 4; ++n) {
            float4 a4 = *(const float4*)&als[ng * 4 + n][m4 * 4];
            av[n][0] = a4.x; av[n][1] = a4.y; av[n][2] = a4.z; av[n][3] = a4.w;
        }
        #pragma unroll
        for (int mm = 0; mm < 4; ++mm) {
            float4 f4 = *(const float4*)(fb + (size_t)(m4 * 4 + mm) * DD);
            float fv[4] = {f4.x, f4.y, f4.z, f4.w};
            #pragma unroll
            for (int n = 0; n < 4; ++n)
                #pragma unroll
                for (int j = 0; j < 4; ++j)
                    acc[n][j] = fmaf(av[n][mm], fv[j], acc[n][j]);
        }
    }
    #pragma unroll
    for (int n = 0; n < 4; ++n)
        *(float4*)&part[((size_t)bm << 18) + (size_t)(bn * 16 + ng * 4 + n) * DD + 4 * dq] =
            make_float4(acc[n][0], acc[n][1], acc[n][2], acc[n][3]);
}

// ---------------- K4: reduce partials -> ctx + stage-2 scores + last-block pool ----------------
// 1024 blocks x 256 thr; block n handles row n. The last block to finish does the
// softmax over N and the pooled sum (device-scope fence + counter).
__global__ __launch_bounds__(256) void reduce_pool_kernel(
    const float* __restrict__ part, const float* __restrict__ wp_w,
    float* __restrict__ ctx, float* __restrict__ score,
    unsigned int* __restrict__ cnt, float* __restrict__ out)
{
    __shared__ float red[4];
    __shared__ float red2[8];
    __shared__ float wl[1024];
    __shared__ int lastFlag;

    const int t = threadIdx.x;
    const int n = blockIdx.x;
    const int lane = t & 63, wid = t >> 6;

    size_t idx = (size_t)n * DD + t;
    float c = 0.f;
    #pragma unroll
    for (int s = 0; s < 8; ++s) c += part[idx + ((size_t)s << 18)];
    ctx[idx] = c;

    float p = c * wp_w[t];
    #pragma unroll
    for (int off = 32; off > 0; off >>= 1) p += __shfl_xor(p, off);
    if (lane == 0) red[wid] = p;
    __syncthreads();
    if (t == 0) score[n] = red[0] + red[1] + red[2] + red[3];

    __threadfence();                    // release ctx/score writes (device scope)
    __syncthreads();
    if (t == 0) {
        unsigned int old = atomicAdd(cnt, 1u);
        lastFlag = (old == gridDim.x - 1);
    }
    __syncthreads();
    if (!lastFlag) return;
    __threadfence();                    // acquire other blocks' writes

    // ---- softmax over N ----
    float s0 = score[t], s1 = score[t + 256], s2 = score[t + 512], s3 = score[t + 768];
    float mx = fmaxf(fmaxf(s0, s1), fmaxf(s2, s3));
    #pragma unroll
    for (int off = 32; off > 0; off >>= 1) mx = fmaxf(mx, __shfl_xor(mx, off));
    if (lane == 0) red2[wid] = mx;
    __syncthreads();
    mx = fmaxf(fmaxf(red2[0], red2[1]), fmaxf(red2[2], red2[3]));

    float e0 = __expf(s0 - mx), e1 = __expf(s1 - mx), e2 = __expf(s2 - mx), e3 = __expf(s3 - mx);
    float se = e0 + e1 + e2 + e3;
    #pragma unroll
    for (int off = 32; off > 0; off >>= 1) se += __shfl_xor(se, off);
    if (lane == 0) red2[4 + wid] = se;
    __syncthreads();
    se = red2[4] + red2[5] + red2[6] + red2[7];
    float invS = rcp_fast(se);

    wl[t] = e0 * invS; wl[t + 256] = e1 * invS; wl[t + 512] = e2 * invS; wl[t + 768] = e3 * invS;
    __syncthreads();

    // ---- pool: out[d] = sum_n alpha_p[n] * ctx[n][d], d = t ----
    float a0 = 0.f, a1 = 0.f, a2 = 0.f, a3 = 0.f;
    #pragma unroll 4
    for (int nn = 0; nn < 256; ++nn) {
        a0 = fmaf(wl[nn],       ctx[(size_t)nn * DD + t],          a0);
        a1 = fmaf(wl[nn + 256], ctx[(size_t)(nn + 256) * DD + t],  a1);
        a2 = fmaf(wl[nn + 512], ctx[(size_t)(nn + 512) * DD + t],  a2);
        a3 = fmaf(wl[nn + 768], ctx[(size_t)(nn + 768) * DD + t],  a3);
    }
    out[t] = (a0 + a1) + (a2 + a3);
}

extern "C" void kernel_launch(void* const* d_in, const int* in_sizes, int n_in,
                              void* d_out, int out_size, void* d_ws, size_t ws_size,
                              hipStream_t stream) {
    const float* f_r  = (const float*)d_in[0];
    const float* f_rp = (const float*)d_in[1];
    const float* W_w  = (const float*)d_in[2];
    const float* W_b  = (const float*)d_in[3];
    const float* Wp_w = (const float*)d_in[4];
    const float* Wp_b = (const float*)d_in[5];
    const float* w_w  = (const float*)d_in[6];
    // d_in[7] = w_b  : cancels in softmax over m
    const float* wp_w = (const float*)d_in[8];
    // d_in[9] = wp_b : cancels in softmax over n
    float* out = (float*)d_out;

    float* ws    = (float*)d_ws;
    float* Eq    = ws;                  // 256K floats
    float* EkT   = ws + 262144;         // 256K
    float* alpha = ws + 524288;         // 1M
    float* part  = ws + 1572864;        // 8 x 256K
    float* ctx   = ws + 3670016;        // 256K
    float* score = ws + 3932160;        // 1K
    unsigned int* cnt = (unsigned int*)(ws + 3933184);

    gemm_exp_kernel<<<256, 256, 0, stream>>>(f_r, W_w, W_b, f_rp, Wp_w, Wp_b, Eq, EkT, cnt);
    score_softmax_kernel<<<512, 512, 0, stream>>>(Eq, EkT, w_w, alpha);
    context_kernel<<<512, 256, 0, stream>>>(alpha, f_rp, part);
    reduce_pool_kernel<<<1024, 256, 0, stream>>>(part, wp_w, ctx, score, cnt, out);
}

// Round 5
// 136.277 us; speedup vs baseline: 1.6377x; 1.6377x over previous
//
#include <hip/hip_runtime.h>

#define NN 1024
#define MM 1024
#define DD 256

typedef float floatx2 __attribute__((ext_vector_type(2)));

__device__ __forceinline__ float rcp_fast(float x) { return __builtin_amdgcn_rcpf(x); }

// ---------------- K1: fused dual GEMM + exp epilogue + g-vector ----------------
// blocks 0..255:  q = f_r @ W_w^T + W_b    -> Eq[n][d]  = exp(2q)   (clamped +-5)
//                 k = f_rp @ Wp_w^T + Wp_b -> EkT[d][m] = exp(2k)   (LDS-transposed)
// blocks 256..259: g[m] = frp[m] . wp_w  (for stage-2 scores in K2); block 256 zeroes out.
__global__ __launch_bounds__(256) void gemm_exp_kernel(
    const float* __restrict__ f_r,  const float* __restrict__ W_w,  const float* __restrict__ W_b,
    const float* __restrict__ f_rp, const float* __restrict__ Wp_w, const float* __restrict__ Wp_b,
    const float* __restrict__ wp_w,
    float* __restrict__ Eq, float* __restrict__ EkT, float* __restrict__ g,
    float* __restrict__ out0)
{
    __shared__ float As[32][36];   // [k][r]
    __shared__ float Bs[32][68];   // [k][d]
    __shared__ float T[64][36];    // k-path transpose buffer [d_local][r_local]

    const int b = blockIdx.x;
    const int t = threadIdx.x;

    if (b >= 256) {                 // ---- g path ----
        const int gb = b - 256;     // 0..3
        if (gb == 0) out0[t] = 0.f; // zero d_out for K4's atomicAdd
        const int m = gb * 256 + t;
        const float4* fm = (const float4*)(f_rp + (size_t)m * DD);
        const float4* wp = (const float4*)wp_w;
        float a0 = 0.f, a1 = 0.f, a2 = 0.f, a3 = 0.f;
        #pragma unroll 8
        for (int j = 0; j < 64; ++j) {
            float4 v = fm[j], w = wp[j];
            a0 = fmaf(v.x, w.x, a0); a1 = fmaf(v.y, w.y, a1);
            a2 = fmaf(v.z, w.z, a2); a3 = fmaf(v.w, w.w, a3);
        }
        g[m] = (a0 + a1) + (a2 + a3);
        return;
    }

    const int mat  = b >> 7;
    const int tile = b & 127;
    const int rt = tile & 31, dt = tile >> 5;
    const float* __restrict__ A    = mat ? f_rp : f_r;
    const float* __restrict__ B    = mat ? Wp_w : W_w;
    const float* __restrict__ bias = mat ? Wp_b : W_b;

    const int tx = t & 15, ty = t >> 4;          // tx -> 4 d-cols, ty -> 2 r-rows
    const int r0 = rt * 32, d0 = dt * 64;
    const int ar = t >> 3, ak = (t & 7) * 4;     // A stage: 32 rows x 32 k
    const int br = t >> 2, bk = (t & 3) * 8;     // B stage: 64 rows x 32 k

    float acc[2][4];
    #pragma unroll
    for (int i = 0; i < 2; ++i)
        #pragma unroll
        for (int j = 0; j < 4; ++j) acc[i][j] = 0.f;

    for (int kk = 0; kk < DD; kk += 32) {
        float4 av  = *(const float4*)(A + (size_t)(r0 + ar) * DD + kk + ak);
        float4 bv0 = *(const float4*)(B + (size_t)(d0 + br) * DD + kk + bk);
        float4 bv1 = *(const float4*)(B + (size_t)(d0 + br) * DD + kk + bk + 4);
        __syncthreads();
        As[ak + 0][ar] = av.x; As[ak + 1][ar] = av.y; As[ak + 2][ar] = av.z; As[ak + 3][ar] = av.w;
        Bs[bk + 0][br] = bv0.x; Bs[bk + 1][br] = bv0.y; Bs[bk + 2][br] = bv0.z; Bs[bk + 3][br] = bv0.w;
        Bs[bk + 4][br] = bv1.x; Bs[bk + 5][br] = bv1.y; Bs[bk + 6][br] = bv1.z; Bs[bk + 7][br] = bv1.w;
        __syncthreads();
        #pragma unroll
        for (int k = 0; k < 32; ++k) {
            float2 a2 = *(const float2*)&As[k][ty * 2];
            float4 b4 = *(const float4*)&Bs[k][tx * 4];
            float aa[2] = {a2.x, a2.y};
            float bb[4] = {b4.x, b4.y, b4.z, b4.w};
            #pragma unroll
            for (int i = 0; i < 2; ++i)
                #pragma unroll
                for (int j = 0; j < 4; ++j)
                    acc[i][j] = fmaf(aa[i], bb[j], acc[i][j]);
        }
    }

    float bj[4];
    #pragma unroll
    for (int j = 0; j < 4; ++j) bj[j] = bias[d0 + tx * 4 + j];

    float e[2][4];
    #pragma unroll
    for (int i = 0; i < 2; ++i)
        #pragma unroll
        for (int j = 0; j < 4; ++j) {
            float v = acc[i][j] + bj[j];
            // +-5: tanh(5)=0.9999092 (error 9e-5, negligible after w-weighting);
            // keeps K2's 4-way product x^4 <= e^80 < fp32 max.
            v = fminf(fmaxf(v, -5.f), 5.f);
            e[i][j] = __expf(2.f * v);
        }

    if (mat == 0) {
        #pragma unroll
        for (int i = 0; i < 2; ++i)
            *(float4*)&Eq[(size_t)(r0 + ty * 2 + i) * DD + d0 + tx * 4] =
                make_float4(e[i][0], e[i][1], e[i][2], e[i][3]);
    } else {
        __syncthreads();
        #pragma unroll
        for (int i = 0; i < 2; ++i)
            #pragma unroll
            for (int j = 0; j < 4; ++j) T[tx * 4 + j][ty * 2 + i] = e[i][j];
        __syncthreads();
        const int dl = t >> 3, rl = (t & 7) * 4;
        #pragma unroll
        for (int h = 0; h < 2; ++h) {
            int dloc = dl + 32 * h;
            float4 tv = *(const float4*)&T[dloc][rl];
            *(float4*)&EkT[(size_t)(d0 + dloc) * MM + r0 + rl] = tv;
        }
    }
}

// ---------------- K2: scores + softmax over m -> alpha, + stage-2 scores ----------------
// s~[n,m] = sum_d (-2 w[d]) / (Eq[n,d]*Ek[m,d] + 1)
// 4-way combining: sum_{i<4} w_i/x_i = (n01*p23 + n23*p01) / (p01*p23)  -> 1 rcp per 4 d.
// j-dimension (4 m-cols) packed as floatx2 pairs -> v_pk_fma_f32.
// Also: score[n] = alpha[n,:] . g   (stage-2 raw scores; wp_b cancels in softmax).
// 512 blocks x 512 thr; block = 2 n-rows; tg = d-half; tm -> m cols 4tm..4tm+3.
__global__ __launch_bounds__(512, 4) void score_softmax_kernel(
    const float* __restrict__ Eq, const float* __restrict__ EkT,
    const float* __restrict__ w_w, const float* __restrict__ g,
    float* __restrict__ alpha, float* __restrict__ score)
{
    __shared__ float eq[2 * DD];
    __shared__ float w2[DD];
    __shared__ float accbuf[8][256];
    __shared__ float redmx[8 * 2];
    __shared__ float redsm[8 * 2];
    __shared__ float redg[4 * 2];

    const int t  = threadIdx.x;
    const int tg = t >> 8;        // d-half
    const int tm = t & 255;       // m cols 4tm..4tm+3
    const int lane = t & 63, wid = t >> 6;
    const int n0 = blockIdx.x * 2;
    const int dh = tg * 128;

    eq[t] = Eq[(size_t)n0 * DD + t];
    if (t < DD) w2[t] = -2.0f * w_w[t];
    __syncthreads();

    const floatx2 one2 = {1.f, 1.f};
    floatx2 accl[2] = {{0.f, 0.f}, {0.f, 0.f}};   // j0,j1 per n
    floatx2 acch[2] = {{0.f, 0.f}, {0.f, 0.f}};   // j2,j3 per n

    const float* ekb = EkT + (size_t)dh * MM + 4 * tm;

    float4 c0 = *(const float4*)(ekb + 0 * MM);
    float4 c1 = *(const float4*)(ekb + 1 * MM);
    float4 c2 = *(const float4*)(ekb + 2 * MM);
    float4 c3 = *(const float4*)(ekb + 3 * MM);

    for (int gi = 0; gi < 32; ++gi) {
        float4 p0 = c0, p1 = c1, p2 = c2, p3 = c3;
        if (gi < 31) {
            const float* nb = ekb + (size_t)(gi * 4 + 4) * MM;
            p0 = *(const float4*)(nb + 0 * MM);
            p1 = *(const float4*)(nb + 1 * MM);
            p2 = *(const float4*)(nb + 2 * MM);
            p3 = *(const float4*)(nb + 3 * MM);
        }
        const int db = gi * 4;
        float4 w4 = *(const float4*)&w2[dh + db];
        float4 qA = *(const float4*)&eq[dh + db];
        float4 qB = *(const float4*)&eq[DD + dh + db];

        floatx2 kv[4][2] = {{{c0.x, c0.y}, {c0.z, c0.w}},
                            {{c1.x, c1.y}, {c1.z, c1.w}},
                            {{c2.x, c2.y}, {c2.z, c2.w}},
                            {{c3.x, c3.y}, {c3.z, c3.w}}};
        float ws[4] = {w4.x, w4.y, w4.z, w4.w};
        float qs[2][4] = {{qA.x, qA.y, qA.z, qA.w}, {qB.x, qB.y, qB.z, qB.w}};

        #pragma unroll
        for (int h = 0; h < 2; ++h) {           // j-halves (lo: j0,j1 / hi: j2,j3)
            #pragma unroll
            for (int n = 0; n < 2; ++n) {
                floatx2 x0 = qs[n][0] * kv[0][h] + one2;
                floatx2 x1 = qs[n][1] * kv[1][h] + one2;
                floatx2 x2 = qs[n][2] * kv[2][h] + one2;
                floatx2 x3 = qs[n][3] * kv[3][h] + one2;
                floatx2 p01 = x0 * x1;
                floatx2 p23 = x2 * x3;
                floatx2 n01 = ws[0] * x1 + ws[1] * x0;
                floatx2 n23 = ws[2] * x3 + ws[3] * x2;
                floatx2 nc  = n01 * p23 + n23 * p01;
                floatx2 pt  = p01 * p23;
                floatx2 r;  r.x = rcp_fast(pt.x);  r.y = rcp_fast(pt.y);
                if (h == 0) accl[n] += nc * r; else acch[n] += nc * r;
            }
        }
        c0 = p0; c1 = p1; c2 = p2; c3 = p3;
    }

    float acc[2][4];
    #pragma unroll
    for (int n = 0; n < 2; ++n) {
        acc[n][0] = accl[n].x; acc[n][1] = accl[n].y;
        acc[n][2] = acch[n].x; acc[n][3] = acch[n].y;
    }

    // combine d-halves
    if (tg == 1) {
        #pragma unroll
        for (int n = 0; n < 2; ++n)
            #pragma unroll
            for (int j = 0; j < 4; ++j) accbuf[n * 4 + j][tm] = acc[n][j];
    }
    __syncthreads();
    if (tg == 0) {
        #pragma unroll
        for (int n = 0; n < 2; ++n)
            #pragma unroll
            for (int j = 0; j < 4; ++j) acc[n][j] += accbuf[n * 4 + j][tm];
    }

    // softmax over m: max
    float mx[2];
    #pragma unroll
    for (int n = 0; n < 2; ++n) {
        mx[n] = (tg == 0) ? fmaxf(fmaxf(acc[n][0], acc[n][1]), fmaxf(acc[n][2], acc[n][3])) : -3e38f;
        #pragma unroll
        for (int off = 32; off > 0; off >>= 1) mx[n] = fmaxf(mx[n], __shfl_xor(mx[n], off));
    }
    if (lane == 0) { redmx[wid * 2] = mx[0]; redmx[wid * 2 + 1] = mx[1]; }
    __syncthreads();
    float MX[2];
    #pragma unroll
    for (int n = 0; n < 2; ++n) {
        float m = redmx[n];
        #pragma unroll
        for (int w = 1; w < 8; ++w) m = fmaxf(m, redmx[w * 2 + n]);
        MX[n] = m;
    }

    // exp + sum
    float e[2][4], sm[2];
    #pragma unroll
    for (int n = 0; n < 2; ++n) {
        sm[n] = 0.f;
        #pragma unroll
        for (int j = 0; j < 4; ++j) {
            e[n][j] = (tg == 0) ? __expf(acc[n][j] - MX[n]) : 0.f;
            sm[n] += e[n][j];
        }
        #pragma unroll
        for (int off = 32; off > 0; off >>= 1) sm[n] += __shfl_xor(sm[n], off);
    }
    if (lane == 0) { redsm[wid * 2] = sm[0]; redsm[wid * 2 + 1] = sm[1]; }
    __syncthreads();
    if (tg == 0) {
        float4 g4 = *(const float4*)&g[4 * tm];
        float sn[2];
        #pragma unroll
        for (int n = 0; n < 2; ++n) {
            float s = redsm[n];
            #pragma unroll
            for (int w = 1; w < 8; ++w) s += redsm[w * 2 + n];
            float inv = rcp_fast(s);
            float a0 = e[n][0] * inv, a1 = e[n][1] * inv, a2 = e[n][2] * inv, a3 = e[n][3] * inv;
            *(float4*)&alpha[(size_t)(n0 + n) * MM + 4 * tm] = make_float4(a0, a1, a2, a3);
            // stage-2 raw score contribution: alpha . g
            sn[n] = fmaf(a0, g4.x, fmaf(a1, g4.y, fmaf(a2, g4.z, a3 * g4.w)));
            #pragma unroll
            for (int off = 32; off > 0; off >>= 1) sn[n] += __shfl_xor(sn[n], off);
        }
        if (lane == 0) { redg[wid * 2] = sn[0]; redg[wid * 2 + 1] = sn[1]; }
    }
    __syncthreads();
    if (t == 0) score[n0]     = redg[0] + redg[2] + redg[4] + redg[6];
    if (t == 1) score[n0 + 1] = redg[1] + redg[3] + redg[5] + redg[7];
}

// ---------------- K3: context GEMM, part[ms] = alpha_tile @ frp_tile ----------------
// tile: 16 n x 256 d, m-split 8 -> 64 x 8 = 512 blocks x 256 thr.
__global__ __launch_bounds__(256) void context_kernel(
    const float* __restrict__ alpha, const float* __restrict__ frp,
    float* __restrict__ part)
{
    __shared__ float als[16][128];   // alpha tile, broadcast reads (wave-uniform row)
    const int t  = threadIdx.x;
    const int bm = blockIdx.x & 7;
    const int bn = blockIdx.x >> 3;
    const int dq = t & 63;           // 4 d-cols: 4dq..4dq+3
    const int ng = t >> 6;           // n-subgroup (== wave id -> broadcast)

    #pragma unroll
    for (int i = 0; i < 2; ++i) {
        int f4i = t + i * 256;
        int row = f4i >> 5, c4 = f4i & 31;
        *(float4*)&als[row][c4 * 4] =
            *(const float4*)&alpha[(size_t)(bn * 16 + row) * MM + bm * 128 + c4 * 4];
    }
    __syncthreads();

    float acc[4][4];
    #pragma unroll
    for (int n = 0; n < 4; ++n)
        #pragma unroll
        for (int j = 0; j < 4; ++j) acc[n][j] = 0.f;

    const float* fb = frp + (size_t)(bm * 128) * DD + 4 * dq;
    for (int m4 = 0; m4 < 32; ++m4) {
        float av[4][4];
        #pragma unroll
        for (int n = 0; n < 4; ++n) {
            float4 a4 = *(const float4*)&als[ng * 4 + n][m4 * 4];
            av[n][0] = a4.x; av[n][1] = a4.y; av[n][2] = a4.z; av[n][3] = a4.w;
        }
        #pragma unroll
        for (int mm = 0; mm < 4; ++mm) {
            float4 f4 = *(const float4*)(fb + (size_t)(m4 * 4 + mm) * DD);
            float fv[4] = {f4.x, f4.y, f4.z, f4.w};
            #pragma unroll
            for (int n = 0; n < 4; ++n)
                #pragma unroll
                for (int j = 0; j < 4; ++j)
                    acc[n][j] = fmaf(av[n][mm], fv[j], acc[n][j]);
        }
    }
    #pragma unroll
    for (int n = 0; n < 4; ++n)
        *(float4*)&part[((size_t)bm << 18) + (size_t)(bn * 16 + ng * 4 + n) * DD + 4 * dq] =
            make_float4(acc[n][0], acc[n][1], acc[n][2], acc[n][3]);
}

// ---------------- K4: softmax over N (redundant per block) + pooled sum ----------------
// 256 blocks x 256 thr; block b handles n-rows 4b..4b+3, reading part directly.
// Every block computes the identical mx/S (same data, same reduction order).
__global__ __launch_bounds__(256) void pool_kernel(
    const float* __restrict__ part, const float* __restrict__ score,
    float* __restrict__ out)
{
    __shared__ float red[8];
    const int t = threadIdx.x, lane = t & 63, wid = t >> 6;
    const int n0 = blockIdx.x * 4;

    float s0 = score[t], s1 = score[t + 256], s2 = score[t + 512], s3 = score[t + 768];
    float mx = fmaxf(fmaxf(s0, s1), fmaxf(s2, s3));
    #pragma unroll
    for (int off = 32; off > 0; off >>= 1) mx = fmaxf(mx, __shfl_xor(mx, off));
    if (lane == 0) red[wid] = mx;
    __syncthreads();
    mx = fmaxf(fmaxf(red[0], red[1]), fmaxf(red[2], red[3]));

    float se = __expf(s0 - mx) + __expf(s1 - mx) + __expf(s2 - mx) + __expf(s3 - mx);
    #pragma unroll
    for (int off = 32; off > 0; off >>= 1) se += __shfl_xor(se, off);
    if (lane == 0) red[4 + wid] = se;
    __syncthreads();
    se = red[4] + red[5] + red[6] + red[7];
    float invS = rcp_fast(se);

    float r = 0.f;
    #pragma unroll
    for (int i = 0; i < 4; ++i) {
        float ap = __expf(score[n0 + i] - mx) * invS;   // wave-uniform broadcast load
        size_t idx = (size_t)(n0 + i) * DD + t;
        float c = 0.f;
        #pragma unroll
        for (int s = 0; s < 8; ++s) c += part[idx + ((size_t)s << 18)];
        r = fmaf(ap, c, r);
    }
    atomicAdd(out + t, r);
}

extern "C" void kernel_launch(void* const* d_in, const int* in_sizes, int n_in,
                              void* d_out, int out_size, void* d_ws, size_t ws_size,
                              hipStream_t stream) {
    const float* f_r  = (const float*)d_in[0];
    const float* f_rp = (const float*)d_in[1];
    const float* W_w  = (const float*)d_in[2];
    const float* W_b  = (const float*)d_in[3];
    const float* Wp_w = (const float*)d_in[4];
    const float* Wp_b = (const float*)d_in[5];
    const float* w_w  = (const float*)d_in[6];
    // d_in[7] = w_b  : cancels in softmax over m
    const float* wp_w = (const float*)d_in[8];
    // d_in[9] = wp_b : cancels in softmax over n
    float* out = (float*)d_out;

    float* ws    = (float*)d_ws;
    float* Eq    = ws;                  // 256K floats
    float* EkT   = ws + 262144;         // 256K
    float* alpha = ws + 524288;         // 1M
    float* part  = ws + 1572864;        // 8 x 256K
    float* score = ws + 3670016;        // 1K
    float* g     = ws + 3671040;        // 1K

    gemm_exp_kernel<<<260, 256, 0, stream>>>(f_r, W_w, W_b, f_rp, Wp_w, Wp_b, wp_w,
                                             Eq, EkT, g, out);
    score_softmax_kernel<<<512, 512, 0, stream>>>(Eq, EkT, w_w, g, alpha, score);
    context_kernel<<<512, 256, 0, stream>>>(alpha, f_rp, part);
    pool_kernel<<<256, 256, 0, stream>>>(part, score, out);
}

// Round 6
// 125.051 us; speedup vs baseline: 1.7847x; 1.0898x over previous
//
#include <hip/hip_runtime.h>

#define NN 1024
#define MM 1024
#define DD 256

typedef float floatx2 __attribute__((ext_vector_type(2)));

__device__ __forceinline__ float rcp_fast(float x) { return __builtin_amdgcn_rcpf(x); }

// ---------------- K1: fused dual GEMM + exp epilogue ----------------
// blocks 0..127:   q = f_r @ W_w^T + W_b    -> Eq[n][d]  = exp(2q)   (clamped +-5)
// blocks 128..255: k = f_rp @ Wp_w^T + Wp_b -> EkT[d][m] = exp(2k)   (LDS-transposed)
// Block 0 also zeroes d_out for K3's atomicAdd.
__global__ __launch_bounds__(256) void gemm_exp_kernel(
    const float* __restrict__ f_r,  const float* __restrict__ W_w,  const float* __restrict__ W_b,
    const float* __restrict__ f_rp, const float* __restrict__ Wp_w, const float* __restrict__ Wp_b,
    float* __restrict__ Eq, float* __restrict__ EkT, float* __restrict__ out0)
{
    __shared__ float As[32][36];   // [k][r]
    __shared__ float Bs[32][68];   // [k][d]
    __shared__ float T[64][36];    // k-path transpose buffer [d_local][r_local]

    const int b = blockIdx.x;
    const int t = threadIdx.x;
    if (b == 0) out0[t] = 0.f;     // zero d_out (256 floats)

    const int mat  = b >> 7;
    const int tile = b & 127;
    const int rt = tile & 31, dt = tile >> 5;
    const float* __restrict__ A    = mat ? f_rp : f_r;
    const float* __restrict__ B    = mat ? Wp_w : W_w;
    const float* __restrict__ bias = mat ? Wp_b : W_b;

    const int tx = t & 15, ty = t >> 4;          // tx -> 4 d-cols, ty -> 2 r-rows
    const int r0 = rt * 32, d0 = dt * 64;
    const int ar = t >> 3, ak = (t & 7) * 4;     // A stage: 32 rows x 32 k
    const int br = t >> 2, bk = (t & 3) * 8;     // B stage: 64 rows x 32 k

    float acc[2][4];
    #pragma unroll
    for (int i = 0; i < 2; ++i)
        #pragma unroll
        for (int j = 0; j < 4; ++j) acc[i][j] = 0.f;

    for (int kk = 0; kk < DD; kk += 32) {
        float4 av  = *(const float4*)(A + (size_t)(r0 + ar) * DD + kk + ak);
        float4 bv0 = *(const float4*)(B + (size_t)(d0 + br) * DD + kk + bk);
        float4 bv1 = *(const float4*)(B + (size_t)(d0 + br) * DD + kk + bk + 4);
        __syncthreads();
        As[ak + 0][ar] = av.x; As[ak + 1][ar] = av.y; As[ak + 2][ar] = av.z; As[ak + 3][ar] = av.w;
        Bs[bk + 0][br] = bv0.x; Bs[bk + 1][br] = bv0.y; Bs[bk + 2][br] = bv0.z; Bs[bk + 3][br] = bv0.w;
        Bs[bk + 4][br] = bv1.x; Bs[bk + 5][br] = bv1.y; Bs[bk + 6][br] = bv1.z; Bs[bk + 7][br] = bv1.w;
        __syncthreads();
        #pragma unroll
        for (int k = 0; k < 32; ++k) {
            float2 a2 = *(const float2*)&As[k][ty * 2];
            float4 b4 = *(const float4*)&Bs[k][tx * 4];
            float aa[2] = {a2.x, a2.y};
            float bb[4] = {b4.x, b4.y, b4.z, b4.w};
            #pragma unroll
            for (int i = 0; i < 2; ++i)
                #pragma unroll
                for (int j = 0; j < 4; ++j)
                    acc[i][j] = fmaf(aa[i], bb[j], acc[i][j]);
        }
    }

    float bj[4];
    #pragma unroll
    for (int j = 0; j < 4; ++j) bj[j] = bias[d0 + tx * 4 + j];

    float e[2][4];
    #pragma unroll
    for (int i = 0; i < 2; ++i)
        #pragma unroll
        for (int j = 0; j < 4; ++j) {
            float v = acc[i][j] + bj[j];
            // +-5: tanh(5)=0.9999092 (error 9e-5, negligible after w-weighting);
            // keeps K2's 4-way product x^4 <= e^80 < fp32 max.
            v = fminf(fmaxf(v, -5.f), 5.f);
            e[i][j] = __expf(2.f * v);
        }

    if (mat == 0) {
        #pragma unroll
        for (int i = 0; i < 2; ++i)
            *(float4*)&Eq[(size_t)(r0 + ty * 2 + i) * DD + d0 + tx * 4] =
                make_float4(e[i][0], e[i][1], e[i][2], e[i][3]);
    } else {
        __syncthreads();
        #pragma unroll
        for (int i = 0; i < 2; ++i)
            #pragma unroll
            for (int j = 0; j < 4; ++j) T[tx * 4 + j][ty * 2 + i] = e[i][j];
        __syncthreads();
        const int dl = t >> 3, rl = (t & 7) * 4;
        #pragma unroll
        for (int h = 0; h < 2; ++h) {
            int dloc = dl + 32 * h;
            float4 tv = *(const float4*)&T[dloc][rl];
            *(float4*)&EkT[(size_t)(d0 + dloc) * MM + r0 + rl] = tv;
        }
    }
}

// ---------------- K2: mega — scores + softmax_M + context + stage-2 score ----------------
// 256 blocks x 1024 thr; block = 4 n-rows, all of m, all of d.
// Phase A (score): tg = t>>8 = d-quarter (64 d each); tm = t&255 -> m cols 4tm..4tm+3.
//   s~[n,m] = sum_d (-2 w[d]) / (Eq[n,d]*Ek[m,d] + 1), 4-way rcp combining, pk-packed.
// Phase B: LDS quarter-combine, softmax over m, alpha -> LDS only.
// Phase C (ctx): cc = t&63 -> 4 d-cols; rr = t>>6 -> 64-m range; ctx = alpha @ frp,
//   LDS range-reduce; stage-2 score[n] = ctx[n] . wp_w.
__global__ __launch_bounds__(1024, 4) void fused_attn_kernel(
    const float* __restrict__ Eq, const float* __restrict__ EkT,
    const float* __restrict__ w_w, const float* __restrict__ frp,
    const float* __restrict__ wp_w,
    float* __restrict__ ctx, float* __restrict__ score)
{
    __shared__ float eq[4 * DD];            //  4 KB
    __shared__ float w2[DD];                //  1 KB
    __shared__ float accbuf[3][16][256];    // 48 KB quarter-combine slabs
    __shared__ float alsm[4][MM];           // 16 KB alpha (block-local only)
    __shared__ float4 ctxred[16][4][64];    // 64 KB range-combine slabs
    __shared__ float redmx[4][4];
    __shared__ float redsm[4][4];
    __shared__ float redsc[16];

    const int t  = threadIdx.x;
    const int tg = t >> 8;        // d-quarter
    const int tm = t & 255;       // m cols 4tm..4tm+3
    const int lane = t & 63, wid = t >> 6;
    const int n0 = blockIdx.x * 4;
    const int dh = tg * 64;

    eq[t] = Eq[(size_t)n0 * DD + t];        // t = n*256 + d exactly
    if (t < DD) w2[t] = -2.0f * w_w[t];
    __syncthreads();

    // ---- Phase A: scores over d-quarter ----
    const floatx2 one2 = {1.f, 1.f};
    floatx2 accl[4] = {{0.f,0.f},{0.f,0.f},{0.f,0.f},{0.f,0.f}};   // j0,j1 per n
    floatx2 acch[4] = {{0.f,0.f},{0.f,0.f},{0.f,0.f},{0.f,0.f}};   // j2,j3 per n

    const float* ekb = EkT + (size_t)dh * MM + 4 * tm;
    float4 c0 = *(const float4*)(ekb + 0 * MM);
    float4 c1 = *(const float4*)(ekb + 1 * MM);
    float4 c2 = *(const float4*)(ekb + 2 * MM);
    float4 c3 = *(const float4*)(ekb + 3 * MM);

    for (int gi = 0; gi < 16; ++gi) {
        float4 p0 = c0, p1 = c1, p2 = c2, p3 = c3;
        if (gi < 15) {
            const float* nb = ekb + (size_t)(gi * 4 + 4) * MM;
            p0 = *(const float4*)(nb + 0 * MM);
            p1 = *(const float4*)(nb + 1 * MM);
            p2 = *(const float4*)(nb + 2 * MM);
            p3 = *(const float4*)(nb + 3 * MM);
        }
        const int db = gi * 4;
        float4 w4 = *(const float4*)&w2[dh + db];
        floatx2 kv[4][2] = {{{c0.x, c0.y}, {c0.z, c0.w}},
                            {{c1.x, c1.y}, {c1.z, c1.w}},
                            {{c2.x, c2.y}, {c2.z, c2.w}},
                            {{c3.x, c3.y}, {c3.z, c3.w}}};
        #pragma unroll
        for (int n = 0; n < 4; ++n) {
            float4 q4 = *(const float4*)&eq[n * DD + dh + db];
            #pragma unroll
            for (int h = 0; h < 2; ++h) {
                floatx2 x0 = q4.x * kv[0][h] + one2;
                floatx2 x1 = q4.y * kv[1][h] + one2;
                floatx2 x2 = q4.z * kv[2][h] + one2;
                floatx2 x3 = q4.w * kv[3][h] + one2;
                floatx2 p01 = x0 * x1;
                floatx2 p23 = x2 * x3;
                floatx2 n01 = w4.x * x1 + w4.y * x0;
                floatx2 n23 = w4.z * x3 + w4.w * x2;
                floatx2 nc  = n01 * p23 + n23 * p01;
                floatx2 pt  = p01 * p23;
                floatx2 r;  r.x = rcp_fast(pt.x);  r.y = rcp_fast(pt.y);
                if (h == 0) accl[n] += nc * r; else acch[n] += nc * r;
            }
        }
        c0 = p0; c1 = p1; c2 = p2; c3 = p3;
    }

    float acc[4][4];
    #pragma unroll
    for (int n = 0; n < 4; ++n) {
        acc[n][0] = accl[n].x; acc[n][1] = accl[n].y;
        acc[n][2] = acch[n].x; acc[n][3] = acch[n].y;
    }

    // ---- Phase B: combine quarters + softmax over m ----
    if (tg > 0) {
        #pragma unroll
        for (int n = 0; n < 4; ++n)
            #pragma unroll
            for (int j = 0; j < 4; ++j) accbuf[tg - 1][n * 4 + j][tm] = acc[n][j];
    }
    __syncthreads();
    if (tg == 0) {
        #pragma unroll
        for (int s = 0; s < 3; ++s)
            #pragma unroll
            for (int n = 0; n < 4; ++n)
                #pragma unroll
                for (int j = 0; j < 4; ++j) acc[n][j] += accbuf[s][n * 4 + j][tm];
        float mx[4];
        #pragma unroll
        for (int n = 0; n < 4; ++n) {
            mx[n] = fmaxf(fmaxf(acc[n][0], acc[n][1]), fmaxf(acc[n][2], acc[n][3]));
            #pragma unroll
            for (int off = 32; off > 0; off >>= 1) mx[n] = fmaxf(mx[n], __shfl_xor(mx[n], off));
            if (lane == 0) redmx[wid][n] = mx[n];
        }
    }
    __syncthreads();
    float e[4][4];
    if (tg == 0) {
        #pragma unroll
        for (int n = 0; n < 4; ++n) {
            float MX = fmaxf(fmaxf(redmx[0][n], redmx[1][n]), fmaxf(redmx[2][n], redmx[3][n]));
            float sm = 0.f;
            #pragma unroll
            for (int j = 0; j < 4; ++j) { e[n][j] = __expf(acc[n][j] - MX); sm += e[n][j]; }
            #pragma unroll
            for (int off = 32; off > 0; off >>= 1) sm += __shfl_xor(sm, off);
            if (lane == 0) redsm[wid][n] = sm;
        }
    }
    __syncthreads();
    if (tg == 0) {
        #pragma unroll
        for (int n = 0; n < 4; ++n) {
            float S = redsm[0][n] + redsm[1][n] + redsm[2][n] + redsm[3][n];
            float inv = rcp_fast(S);
            #pragma unroll
            for (int j = 0; j < 4; ++j) alsm[n][4 * tm + j] = e[n][j] * inv;
        }
    }
    __syncthreads();    // alpha ready in LDS

    // ---- Phase C: ctx = alpha @ frp (m-range split), then stage-2 score ----
    const int cc = t & 63;        // d-cols 4cc..4cc+3
    const int rr = t >> 6;        // m-range rr*64 .. +63
    const int m0 = rr * 64;
    floatx2 axl[4] = {{0.f,0.f},{0.f,0.f},{0.f,0.f},{0.f,0.f}};
    floatx2 axh[4] = {{0.f,0.f},{0.f,0.f},{0.f,0.f},{0.f,0.f}};
    const float* fb = frp + (size_t)m0 * DD + 4 * cc;
    for (int m4 = 0; m4 < 16; ++m4) {
        float alv[4][4];
        #pragma unroll
        for (int n = 0; n < 4; ++n) {
            float4 a4 = *(const float4*)&alsm[n][m0 + m4 * 4];
            alv[n][0] = a4.x; alv[n][1] = a4.y; alv[n][2] = a4.z; alv[n][3] = a4.w;
        }
        #pragma unroll
        for (int mm = 0; mm < 4; ++mm) {
            float4 f = *(const float4*)(fb + (size_t)(m4 * 4 + mm) * DD);
            floatx2 fl = {f.x, f.y}, fh = {f.z, f.w};
            #pragma unroll
            for (int n = 0; n < 4; ++n) {
                axl[n] += alv[n][mm] * fl;
                axh[n] += alv[n][mm] * fh;
            }
        }
    }
    #pragma unroll
    for (int n = 0; n < 4; ++n)
        ctxred[rr][n][cc] = make_float4(axl[n].x, axl[n].y, axh[n].x, axh[n].y);
    __syncthreads();

    // final reduce: thread t -> (n = t>>8, d = t&255)
    const int nn = t >> 8, d = t & 255;
    float s = 0.f;
    #pragma unroll
    for (int r = 0; r < 16; ++r)
        s += ((const float*)&ctxred[r][nn][d >> 2])[d & 3];
    ctx[(size_t)(n0 + nn) * DD + d] = s;

    float p = s * wp_w[d];
    #pragma unroll
    for (int off = 32; off > 0; off >>= 1) p += __shfl_xor(p, off);
    if (lane == 0) redsc[wid] = p;
    __syncthreads();
    if (t < 4) score[n0 + t] = redsc[4 * t] + redsc[4 * t + 1] + redsc[4 * t + 2] + redsc[4 * t + 3];
}

// ---------------- K3: softmax over N (redundant per block) + pooled sum ----------------
// 256 blocks x 256 thr; block b handles n-rows 4b..4b+3.
// Every block computes the identical mx/S (same data, same reduction order).
__global__ __launch_bounds__(256) void pool_kernel(
    const float* __restrict__ ctx, const float* __restrict__ score,
    float* __restrict__ out)
{
    __shared__ float red[8];
    const int t = threadIdx.x, lane = t & 63, wid = t >> 6;
    const int n0 = blockIdx.x * 4;

    float s0 = score[t], s1 = score[t + 256], s2 = score[t + 512], s3 = score[t + 768];
    float mx = fmaxf(fmaxf(s0, s1), fmaxf(s2, s3));
    #pragma unroll
    for (int off = 32; off > 0; off >>= 1) mx = fmaxf(mx, __shfl_xor(mx, off));
    if (lane == 0) red[wid] = mx;
    __syncthreads();
    mx = fmaxf(fmaxf(red[0], red[1]), fmaxf(red[2], red[3]));

    float se = __expf(s0 - mx) + __expf(s1 - mx) + __expf(s2 - mx) + __expf(s3 - mx);
    #pragma unroll
    for (int off = 32; off > 0; off >>= 1) se += __shfl_xor(se, off);
    if (lane == 0) red[4 + wid] = se;
    __syncthreads();
    se = red[4] + red[5] + red[6] + red[7];
    float invS = rcp_fast(se);

    float r = 0.f;
    #pragma unroll
    for (int i = 0; i < 4; ++i) {
        float ap = __expf(score[n0 + i] - mx) * invS;   // wave-uniform broadcast load
        r = fmaf(ap, ctx[(size_t)(n0 + i) * DD + t], r);
    }
    atomicAdd(out + t, r);
}

extern "C" void kernel_launch(void* const* d_in, const int* in_sizes, int n_in,
                              void* d_out, int out_size, void* d_ws, size_t ws_size,
                              hipStream_t stream) {
    const float* f_r  = (const float*)d_in[0];
    const float* f_rp = (const float*)d_in[1];
    const float* W_w  = (const float*)d_in[2];
    const float* W_b  = (const float*)d_in[3];
    const float* Wp_w = (const float*)d_in[4];
    const float* Wp_b = (const float*)d_in[5];
    const float* w_w  = (const float*)d_in[6];
    // d_in[7] = w_b  : cancels in softmax over m
    const float* wp_w = (const float*)d_in[8];
    // d_in[9] = wp_b : cancels in softmax over n
    float* out = (float*)d_out;

    float* ws    = (float*)d_ws;
    float* Eq    = ws;                  // 256K floats
    float* EkT   = ws + 262144;         // 256K
    float* ctx   = ws + 524288;         // 256K
    float* score = ws + 786432;         // 1K

    gemm_exp_kernel<<<256, 256, 0, stream>>>(f_r, W_w, W_b, f_rp, Wp_w, Wp_b, Eq, EkT, out);
    fused_attn_kernel<<<256, 1024, 0, stream>>>(Eq, EkT, w_w, f_rp, wp_w, ctx, score);
    pool_kernel<<<256, 256, 0, stream>>>(ctx, score, out);
}

// Round 7
// 122.780 us; speedup vs baseline: 1.8177x; 1.0185x over previous
//
#include <hip/hip_runtime.h>

#define NN 1024
#define MM 1024
#define DD 256

typedef float floatx2 __attribute__((ext_vector_type(2)));

__device__ __forceinline__ float rcp_fast(float x) { return __builtin_amdgcn_rcpf(x); }

// ---------------- K1: fused dual GEMM + exp epilogue ----------------
// blocks 0..127:   q = f_r @ W_w^T + W_b    -> Eq[n][d]  = exp(2q)   (clamped +-5)
// blocks 128..255: k = f_rp @ Wp_w^T + Wp_b -> EkT[d][m] = exp(2k)   (LDS-transposed)
// Block 0 also zeroes d_out for K3's atomicAdd.
__global__ __launch_bounds__(256) void gemm_exp_kernel(
    const float* __restrict__ f_r,  const float* __restrict__ W_w,  const float* __restrict__ W_b,
    const float* __restrict__ f_rp, const float* __restrict__ Wp_w, const float* __restrict__ Wp_b,
    float* __restrict__ Eq, float* __restrict__ EkT, float* __restrict__ out0)
{
    __shared__ float As[32][36];   // [k][r]
    __shared__ float Bs[32][68];   // [k][d]
    __shared__ float T[64][36];    // k-path transpose buffer [d_local][r_local]

    const int b = blockIdx.x;
    const int t = threadIdx.x;
    if (b == 0) out0[t] = 0.f;     // zero d_out (256 floats)

    const int mat  = b >> 7;
    const int tile = b & 127;
    const int rt = tile & 31, dt = tile >> 5;
    const float* __restrict__ A    = mat ? f_rp : f_r;
    const float* __restrict__ B    = mat ? Wp_w : W_w;
    const float* __restrict__ bias = mat ? Wp_b : W_b;

    const int tx = t & 15, ty = t >> 4;          // tx -> 4 d-cols, ty -> 2 r-rows
    const int r0 = rt * 32, d0 = dt * 64;
    const int ar = t >> 3, ak = (t & 7) * 4;     // A stage: 32 rows x 32 k
    const int br = t >> 2, bk = (t & 3) * 8;     // B stage: 64 rows x 32 k

    float acc[2][4];
    #pragma unroll
    for (int i = 0; i < 2; ++i)
        #pragma unroll
        for (int j = 0; j < 4; ++j) acc[i][j] = 0.f;

    for (int kk = 0; kk < DD; kk += 32) {
        float4 av  = *(const float4*)(A + (size_t)(r0 + ar) * DD + kk + ak);
        float4 bv0 = *(const float4*)(B + (size_t)(d0 + br) * DD + kk + bk);
        float4 bv1 = *(const float4*)(B + (size_t)(d0 + br) * DD + kk + bk + 4);
        __syncthreads();
        As[ak + 0][ar] = av.x; As[ak + 1][ar] = av.y; As[ak + 2][ar] = av.z; As[ak + 3][ar] = av.w;
        Bs[bk + 0][br] = bv0.x; Bs[bk + 1][br] = bv0.y; Bs[bk + 2][br] = bv0.z; Bs[bk + 3][br] = bv0.w;
        Bs[bk + 4][br] = bv1.x; Bs[bk + 5][br] = bv1.y; Bs[bk + 6][br] = bv1.z; Bs[bk + 7][br] = bv1.w;
        __syncthreads();
        #pragma unroll
        for (int k = 0; k < 32; ++k) {
            float2 a2 = *(const float2*)&As[k][ty * 2];
            float4 b4 = *(const float4*)&Bs[k][tx * 4];
            float aa[2] = {a2.x, a2.y};
            float bb[4] = {b4.x, b4.y, b4.z, b4.w};
            #pragma unroll
            for (int i = 0; i < 2; ++i)
                #pragma unroll
                for (int j = 0; j < 4; ++j)
                    acc[i][j] = fmaf(aa[i], bb[j], acc[i][j]);
        }
    }

    float bj[4];
    #pragma unroll
    for (int j = 0; j < 4; ++j) bj[j] = bias[d0 + tx * 4 + j];

    float e[2][4];
    #pragma unroll
    for (int i = 0; i < 2; ++i)
        #pragma unroll
        for (int j = 0; j < 4; ++j) {
            float v = acc[i][j] + bj[j];
            // +-5: tanh(5)=0.9999092 (error 9e-5, negligible after w-weighting);
            // keeps K2's 4-way product x^4 <= e^80 < fp32 max.
            v = fminf(fmaxf(v, -5.f), 5.f);
            e[i][j] = __expf(2.f * v);
        }

    if (mat == 0) {
        #pragma unroll
        for (int i = 0; i < 2; ++i)
            *(float4*)&Eq[(size_t)(r0 + ty * 2 + i) * DD + d0 + tx * 4] =
                make_float4(e[i][0], e[i][1], e[i][2], e[i][3]);
    } else {
        __syncthreads();
        #pragma unroll
        for (int i = 0; i < 2; ++i)
            #pragma unroll
            for (int j = 0; j < 4; ++j) T[tx * 4 + j][ty * 2 + i] = e[i][j];
        __syncthreads();
        const int dl = t >> 3, rl = (t & 7) * 4;
        #pragma unroll
        for (int h = 0; h < 2; ++h) {
            int dloc = dl + 32 * h;
            float4 tv = *(const float4*)&T[dloc][rl];
            *(float4*)&EkT[(size_t)(d0 + dloc) * MM + r0 + rl] = tv;
        }
    }
}

// ---------------- K2: mega — scores + softmax_M + context + stage-2 score ----------------
// 256 blocks x 1024 thr; block = 4 n-rows, all of m, all of d.
// Phase A: tg = d-quarter; tm -> m cols 4tm..4tm+3. q/w via wave-uniform SCALAR loads
//   (readfirstlane'd addresses -> s_load path); no LDS in the hot loop.
//   s~[n,m] = -2 * sum_d w[d] / (Eq[n,d]*Ek[m,d] + 1), 4-way rcp combining, pk-packed.
// Phase B: tg g owns row g: 4-slab combine + softmax over m, alpha -> LDS.
// Phase C: cc = t&63 -> 4 d-cols; rr = t>>6 -> 64-m range; ctx = alpha @ frp,
//   LDS range-reduce; stage-2 score[n] = ctx[n] . wp_w.
__global__ __launch_bounds__(1024, 4) void fused_attn_kernel(
    const float* __restrict__ Eq, const float* __restrict__ EkT,
    const float* __restrict__ w_w, const float* __restrict__ frp,
    const float* __restrict__ wp_w,
    float* __restrict__ ctx, float* __restrict__ score)
{
    __shared__ float accbuf[4][16][256];    // 64 KB quarter slabs
    __shared__ float alsm[4][MM];           // 16 KB alpha (block-local only)
    __shared__ float4 ctxred[16][4][64];    // 64 KB range-combine slabs
    __shared__ float redmx[4][4];
    __shared__ float redsm[4][4];
    __shared__ float redsc[16];

    const int t  = threadIdx.x;
    const int tg = t >> 8;        // d-quarter
    const int tm = t & 255;       // m cols 4tm..4tm+3
    const int n0 = blockIdx.x * 4;

    // wave-uniform scalar bases (tg constant within a wave)
    const int dh = __builtin_amdgcn_readfirstlane(tg * 64);
    const float* __restrict__ eqb = Eq + (size_t)n0 * DD + dh;   // + n*DD + db
    const float* __restrict__ wwb = w_w + dh;                    // + db

    // ---- Phase A: scores over d-quarter ----
    const floatx2 one2 = {1.f, 1.f};
    floatx2 accl[4] = {{0.f,0.f},{0.f,0.f},{0.f,0.f},{0.f,0.f}};   // j0,j1 per n
    floatx2 acch[4] = {{0.f,0.f},{0.f,0.f},{0.f,0.f},{0.f,0.f}};   // j2,j3 per n

    const float* ekb = EkT + (size_t)dh * MM + 4 * tm;
    float4 c0 = *(const float4*)(ekb + 0 * MM);
    float4 c1 = *(const float4*)(ekb + 1 * MM);
    float4 c2 = *(const float4*)(ekb + 2 * MM);
    float4 c3 = *(const float4*)(ekb + 3 * MM);

    for (int gi = 0; gi < 16; ++gi) {
        float4 p0 = c0, p1 = c1, p2 = c2, p3 = c3;
        if (gi < 15) {
            const float* nb = ekb + (size_t)(gi * 4 + 4) * MM;
            p0 = *(const float4*)(nb + 0 * MM);
            p1 = *(const float4*)(nb + 1 * MM);
            p2 = *(const float4*)(nb + 2 * MM);
            p3 = *(const float4*)(nb + 3 * MM);
        }
        const int db = gi * 4;
        float4 w4 = *(const float4*)(wwb + db);            // scalar (uniform)
        floatx2 kv[4][2] = {{{c0.x, c0.y}, {c0.z, c0.w}},
                            {{c1.x, c1.y}, {c1.z, c1.w}},
                            {{c2.x, c2.y}, {c2.z, c2.w}},
                            {{c3.x, c3.y}, {c3.z, c3.w}}};
        #pragma unroll
        for (int n = 0; n < 4; ++n) {
            float4 q4 = *(const float4*)(eqb + n * DD + db);   // scalar (uniform)
            #pragma unroll
            for (int h = 0; h < 2; ++h) {
                floatx2 x0 = q4.x * kv[0][h] + one2;
                floatx2 x1 = q4.y * kv[1][h] + one2;
                floatx2 x2 = q4.z * kv[2][h] + one2;
                floatx2 x3 = q4.w * kv[3][h] + one2;
                floatx2 p01 = x0 * x1;
                floatx2 p23 = x2 * x3;
                floatx2 n01 = w4.x * x1 + w4.y * x0;
                floatx2 n23 = w4.z * x3 + w4.w * x2;
                floatx2 nc  = n01 * p23 + n23 * p01;
                floatx2 pt  = p01 * p23;
                floatx2 r;  r.x = rcp_fast(pt.x);  r.y = rcp_fast(pt.y);
                if (h == 0) accl[n] += nc * r; else acch[n] += nc * r;
            }
        }
        c0 = p0; c1 = p1; c2 = p2; c3 = p3;
    }

    // fold the (-2 w) scaling here instead of inside the loop
    float acc[4][4];
    #pragma unroll
    for (int n = 0; n < 4; ++n) {
        acc[n][0] = -2.f * accl[n].x; acc[n][1] = -2.f * accl[n].y;
        acc[n][2] = -2.f * acch[n].x; acc[n][3] = -2.f * acch[n].y;
    }

    // ---- Phase B: all-tg combine + softmax; tg g owns row g ----
    #pragma unroll
    for (int n = 0; n < 4; ++n)
        #pragma unroll
        for (int j = 0; j < 4; ++j) accbuf[tg][n * 4 + j][tm] = acc[n][j];
    __syncthreads();

    const int g = tg;                  // row owned by this quarter
    const int w4id = (t >> 6) & 3;     // wave index within the tg group
    const int lane = t & 63;
    float aj[4];
    #pragma unroll
    for (int j = 0; j < 4; ++j)
        aj[j] = accbuf[0][g * 4 + j][tm] + accbuf[1][g * 4 + j][tm]
              + accbuf[2][g * 4 + j][tm] + accbuf[3][g * 4 + j][tm];

    float mx = fmaxf(fmaxf(aj[0], aj[1]), fmaxf(aj[2], aj[3]));
    #pragma unroll
    for (int off = 32; off > 0; off >>= 1) mx = fmaxf(mx, __shfl_xor(mx, off));
    if (lane == 0) redmx[g][w4id] = mx;
    __syncthreads();
    const float MX = fmaxf(fmaxf(redmx[g][0], redmx[g][1]), fmaxf(redmx[g][2], redmx[g][3]));

    float e[4], sm = 0.f;
    #pragma unroll
    for (int j = 0; j < 4; ++j) { e[j] = __expf(aj[j] - MX); sm += e[j]; }
    #pragma unroll
    for (int off = 32; off > 0; off >>= 1) sm += __shfl_xor(sm, off);
    if (lane == 0) redsm[g][w4id] = sm;
    __syncthreads();
    const float S = redsm[g][0] + redsm[g][1] + redsm[g][2] + redsm[g][3];
    const float inv = rcp_fast(S);
    *(float4*)&alsm[g][4 * tm] = make_float4(e[0] * inv, e[1] * inv, e[2] * inv, e[3] * inv);
    __syncthreads();    // alpha ready in LDS

    // ---- Phase C: ctx = alpha @ frp (m-range split), then stage-2 score ----
    const int cc = t & 63;        // d-cols 4cc..4cc+3
    const int rr = t >> 6;        // m-range rr*64 .. +63
    const int m0 = rr * 64;
    floatx2 axl[4] = {{0.f,0.f},{0.f,0.f},{0.f,0.f},{0.f,0.f}};
    floatx2 axh[4] = {{0.f,0.f},{0.f,0.f},{0.f,0.f},{0.f,0.f}};
    const float* fb = frp + (size_t)m0 * DD + 4 * cc;
    for (int m4 = 0; m4 < 16; ++m4) {
        float alv[4][4];
        #pragma unroll
        for (int n = 0; n < 4; ++n) {
            float4 a4 = *(const float4*)&alsm[n][m0 + m4 * 4];
            alv[n][0] = a4.x; alv[n][1] = a4.y; alv[n][2] = a4.z; alv[n][3] = a4.w;
        }
        #pragma unroll
        for (int mm = 0; mm < 4; ++mm) {
            float4 f = *(const float4*)(fb + (size_t)(m4 * 4 + mm) * DD);
            floatx2 fl = {f.x, f.y}, fh = {f.z, f.w};
            #pragma unroll
            for (int n = 0; n < 4; ++n) {
                axl[n] += alv[n][mm] * fl;
                axh[n] += alv[n][mm] * fh;
            }
        }
    }
    #pragma unroll
    for (int n = 0; n < 4; ++n)
        ctxred[rr][n][cc] = make_float4(axl[n].x, axl[n].y, axh[n].x, axh[n].y);
    __syncthreads();

    // final reduce: thread t -> (n = t>>8, d = t&255)
    const int nn = t >> 8, d = t & 255;
    float s = 0.f;
    #pragma unroll
    for (int r = 0; r < 16; ++r)
        s += ((const float*)&ctxred[r][nn][d >> 2])[d & 3];
    ctx[(size_t)(n0 + nn) * DD + d] = s;

    float p = s * wp_w[d];
    #pragma unroll
    for (int off = 32; off > 0; off >>= 1) p += __shfl_xor(p, off);
    if (lane == 0) redsc[t >> 6] = p;
    __syncthreads();
    if (t < 4) score[n0 + t] = redsc[4 * t] + redsc[4 * t + 1] + redsc[4 * t + 2] + redsc[4 * t + 3];
}

// ---------------- K3: softmax over N (redundant per block) + pooled sum ----------------
// 256 blocks x 256 thr; block b handles n-rows 4b..4b+3.
// Every block computes the identical mx/S (same data, same reduction order).
__global__ __launch_bounds__(256) void pool_kernel(
    const float* __restrict__ ctx, const float* __restrict__ score,
    float* __restrict__ out)
{
    __shared__ float red[8];
    const int t = threadIdx.x, lane = t & 63, wid = t >> 6;
    const int n0 = blockIdx.x * 4;

    float s0 = score[t], s1 = score[t + 256], s2 = score[t + 512], s3 = score[t + 768];
    float mx = fmaxf(fmaxf(s0, s1), fmaxf(s2, s3));
    #pragma unroll
    for (int off = 32; off > 0; off >>= 1) mx = fmaxf(mx, __shfl_xor(mx, off));
    if (lane == 0) red[wid] = mx;
    __syncthreads();
    mx = fmaxf(fmaxf(red[0], red[1]), fmaxf(red[2], red[3]));

    float se = __expf(s0 - mx) + __expf(s1 - mx) + __expf(s2 - mx) + __expf(s3 - mx);
    #pragma unroll
    for (int off = 32; off > 0; off >>= 1) se += __shfl_xor(se, off);
    if (lane == 0) red[4 + wid] = se;
    __syncthreads();
    se = red[4] + red[5] + red[6] + red[7];
    float invS = rcp_fast(se);

    float r = 0.f;
    #pragma unroll
    for (int i = 0; i < 4; ++i) {
        float ap = __expf(score[n0 + i] - mx) * invS;   // wave-uniform broadcast load
        r = fmaf(ap, ctx[(size_t)(n0 + i) * DD + t], r);
    }
    atomicAdd(out + t, r);
}

extern "C" void kernel_launch(void* const* d_in, const int* in_sizes, int n_in,
                              void* d_out, int out_size, void* d_ws, size_t ws_size,
                              hipStream_t stream) {
    const float* f_r  = (const float*)d_in[0];
    const float* f_rp = (const float*)d_in[1];
    const float* W_w  = (const float*)d_in[2];
    const float* W_b  = (const float*)d_in[3];
    const float* Wp_w = (const float*)d_in[4];
    const float* Wp_b = (const float*)d_in[5];
    const float* w_w  = (const float*)d_in[6];
    // d_in[7] = w_b  : cancels in softmax over m
    const float* wp_w = (const float*)d_in[8];
    // d_in[9] = wp_b : cancels in softmax over n
    float* out = (float*)d_out;

    float* ws    = (float*)d_ws;
    float* Eq    = ws;                  // 256K floats
    float* EkT   = ws + 262144;         // 256K
    float* ctx   = ws + 524288;         // 256K
    float* score = ws + 786432;         // 1K

    gemm_exp_kernel<<<256, 256, 0, stream>>>(f_r, W_w, W_b, f_rp, Wp_w, Wp_b, Eq, EkT, out);
    fused_attn_kernel<<<256, 1024, 0, stream>>>(Eq, EkT, w_w, f_rp, wp_w, ctx, score);
    pool_kernel<<<256, 256, 0, stream>>>(ctx, score, out);
}